// Round 1
// baseline (8664.825 us; speedup 1.0000x reference)
//
#include <hip/hip_runtime.h>
#include <hip/hip_bf16.h>

#define Bb 64
#define Tt 256
#define Ii 256
#define Hh 512
#define Cc 1000

typedef float f4 __attribute__((ext_vector_type(4)));
typedef short s8 __attribute__((ext_vector_type(8)));

__device__ __forceinline__ unsigned short f2bf(float f) {
  union { float f; unsigned u; } v; v.f = f;
  return (unsigned short)((v.u + 0x7FFFu + ((v.u >> 16) & 1u)) >> 16);
}
__device__ __forceinline__ float sigf(float x) {
  return __builtin_amdgcn_rcpf(1.f + __expf(-x));
}
__device__ __forceinline__ float tanhs(float x) {
  float ax = fabsf(x);
  float e = __expf(-2.f * ax);
  float r = (1.f - e) * __builtin_amdgcn_rcpf(1.f + e);
  return copysignf(r, x);
}

struct LP {
  const float* Wih[3]; const float* Whh[3];
  const float* bih[3]; const float* bhh[3];
  const unsigned short* xb;
  unsigned short* y0; unsigned short* y1; unsigned short* y2;
  unsigned* flags;  // [3][256] producer counters
};

__global__ void zero_flags(unsigned* f) {
  for (int i = threadIdx.x; i < 3 * Tt; i += 256) f[i] = 0;
}

__global__ void cvt_x_kernel(const float* __restrict__ x, unsigned short* __restrict__ xb) {
  int i = blockIdx.x * 256 + threadIdx.x;  // 524288 groups of 8 floats
  const float* s = x + (size_t)i * 8;
  s8 t;
#pragma unroll
  for (int q = 0; q < 8; ++q) t[q] = (short)f2bf(s[q]);
  *(s8*)(xb + (size_t)i * 8) = t;
}

__global__ void bias_init_kernel(const float* __restrict__ fcb, float* __restrict__ out) {
  int i = blockIdx.x * 256 + threadIdx.x;
  if (i < Bb * Cc) out[i] = fcb[i % Cc];
}

// 192 blocks: block = layer*64 + n-slice.  Each block: 8 h-columns x 64 batches,
// weights (32 gate-rows x K) bf16 in LDS, c-state in regs, flag-synced scan over t.
__launch_bounds__(256)
__global__ void lstm_kernel(LP p) {
  const int bid = blockIdx.x;
  const int layer = bid >> 6;
  const int n0 = (bid & 63) * 8;
  const int tid = threadIdx.x;
  const int lane = tid & 63;
  const int wv = tid >> 6;

  __shared__ unsigned short Wh[32 * Hh];  // 32 KB, rows r=4n'+g, XOR-swizzled
  __shared__ unsigned short Wi[32 * Hh];  // 32 KB (layer0 uses 32x256)

  const int Kin = (layer == 0) ? Ii : Hh;

  {  // stage W_hh slice -> LDS (fp32 -> bf16, swizzle ((r&7)<<4) on byte addr)
    const float* wsrc = p.Whh[layer];
    for (int idx = tid; idx < 32 * (Hh / 8); idx += 256) {
      int r = idx >> 6;
      int kk = (idx & 63) << 3;
      int j = (r & 3) * Hh + n0 + (r >> 2);
      const float* s = wsrc + (size_t)j * Hh + kk;
      s8 t;
#pragma unroll
      for (int q = 0; q < 8; ++q) t[q] = (short)f2bf(s[q]);
      int byt = ((r * Hh + kk) * 2) ^ ((r & 7) << 4);
      *(s8*)((char*)Wh + byt) = t;
    }
    const float* wsi = p.Wih[layer];
    int kd8 = Kin >> 3;
    for (int idx = tid; idx < 32 * kd8; idx += 256) {
      int r = idx / kd8;
      int kk = (idx - r * kd8) << 3;
      int j = (r & 3) * Hh + n0 + (r >> 2);
      const float* s = wsi + (size_t)j * Kin + kk;
      s8 t;
#pragma unroll
      for (int q = 0; q < 8; ++q) t[q] = (short)f2bf(s[q]);
      int byt = ((r * Kin + kk) * 2) ^ ((r & 7) << 4);
      *(s8*)((char*)Wi + byt) = t;
    }
  }

  float bv0[4], bv1[4];
  {
    int nn = lane >> 4;
#pragma unroll
    for (int g = 0; g < 4; ++g) {
      bv0[g] = p.bih[layer][g * Hh + n0 + nn] + p.bhh[layer][g * Hh + n0 + nn];
      bv1[g] = p.bih[layer][g * Hh + n0 + 4 + nn] + p.bhh[layer][g * Hh + n0 + 4 + nn];
    }
  }
  float cs0 = 0.f, cs1 = 0.f;
  __syncthreads();

  const int bmine = wv * 16 + (lane & 15);   // this lane's batch (B-frag col)
  const int ksub = (lane >> 4) * 8;          // k offset inside 32-chunk
  const int arow = lane & 15;                // A-frag row within tile
  const int aswz = (arow & 7) << 4;

  unsigned short* ybufs[3] = {p.y0, p.y1, p.y2};
  unsigned short* yl = ybufs[layer];
  const unsigned short* yin = (layer == 0) ? p.xb : ybufs[layer - 1];
  const size_t yin_row = (layer == 0) ? (size_t)(Tt * Ii) : (size_t)(Tt * Hh);
  unsigned* fl_in = p.flags + (layer - 1) * Tt;
  unsigned* fl_my = p.flags + layer * Tt;

  for (int t = 0; t < Tt; ++t) {
    if (layer > 0 && tid == 0) {  // wait: input y[t] complete (64 producers)
      while (__hip_atomic_load(fl_in + t, __ATOMIC_RELAXED, __HIP_MEMORY_SCOPE_AGENT) < 64u)
        __builtin_amdgcn_s_sleep(2);
      __threadfence();
    }
    if (t > 0 && tid == 64) {     // wait (parallel, wave 1): own-layer h[t-1]
      while (__hip_atomic_load(fl_my + (t - 1), __ATOMIC_RELAXED, __HIP_MEMORY_SCOPE_AGENT) < 64u)
        __builtin_amdgcn_s_sleep(2);
      __threadfence();
    }
    __syncthreads();

    f4 a0 = {0.f, 0.f, 0.f, 0.f};
    f4 a1 = {0.f, 0.f, 0.f, 0.f};

    if (t > 0) {  // recurrent: gates^T += Whh_slice * h[t-1]^T
      const unsigned short* hr = yl + ((size_t)bmine * Tt + (t - 1)) * Hh + ksub;
#pragma unroll 4
      for (int kc = 0; kc < 16; ++kc) {
        s8 bf = *(const s8*)(hr + kc * 32);
        int cb = kc * 64 + ksub * 2;
        s8 wa0 = *(const s8*)((const char*)Wh + ((arow * 1024 + cb) ^ aswz));
        s8 wa1 = *(const s8*)((const char*)Wh + (((arow + 16) * 1024 + cb) ^ aswz));
        a0 = __builtin_amdgcn_mfma_f32_16x16x32_bf16(wa0, bf, a0, 0, 0, 0);
        a1 = __builtin_amdgcn_mfma_f32_16x16x32_bf16(wa1, bf, a1, 0, 0, 0);
      }
    }
    {  // input: gates^T += Wih_slice * in[t]^T
      const unsigned short* xr = yin + (size_t)bmine * yin_row + (size_t)t * Kin + ksub;
      if (layer == 0) {
#pragma unroll 4
        for (int kc = 0; kc < 8; ++kc) {
          s8 bf = *(const s8*)(xr + kc * 32);
          int cb = kc * 64 + ksub * 2;
          s8 wa0 = *(const s8*)((const char*)Wi + ((arow * 512 + cb) ^ aswz));
          s8 wa1 = *(const s8*)((const char*)Wi + (((arow + 16) * 512 + cb) ^ aswz));
          a0 = __builtin_amdgcn_mfma_f32_16x16x32_bf16(wa0, bf, a0, 0, 0, 0);
          a1 = __builtin_amdgcn_mfma_f32_16x16x32_bf16(wa1, bf, a1, 0, 0, 0);
        }
      } else {
#pragma unroll 4
        for (int kc = 0; kc < 16; ++kc) {
          s8 bf = *(const s8*)(xr + kc * 32);
          int cb = kc * 64 + ksub * 2;
          s8 wa0 = *(const s8*)((const char*)Wi + ((arow * 1024 + cb) ^ aswz));
          s8 wa1 = *(const s8*)((const char*)Wi + (((arow + 16) * 1024 + cb) ^ aswz));
          a0 = __builtin_amdgcn_mfma_f32_16x16x32_bf16(wa0, bf, a0, 0, 0, 0);
          a1 = __builtin_amdgcn_mfma_f32_16x16x32_bf16(wa1, bf, a1, 0, 0, 0);
        }
      }
    }

    // pointwise LSTM: lane's 4 acc regs = {i,f,g,o} of (b=bmine, n'=4m+(lane>>4))
    unsigned short* yw = yl + ((size_t)bmine * Tt + t) * Hh + n0 + (lane >> 4);
    {
      float pi = a0[0] + bv0[0], pf = a0[1] + bv0[1], pg = a0[2] + bv0[2], po = a0[3] + bv0[3];
      float ii = sigf(pi), ff = sigf(pf), gg = tanhs(pg), oo = sigf(po);
      float c = ff * cs0 + ii * gg; cs0 = c;
      yw[0] = f2bf(oo * tanhs(c));
      pi = a1[0] + bv1[0]; pf = a1[1] + bv1[1]; pg = a1[2] + bv1[2]; po = a1[3] + bv1[3];
      ii = sigf(pi); ff = sigf(pf); gg = tanhs(pg); oo = sigf(po);
      c = ff * cs1 + ii * gg; cs1 = c;
      yw[4] = f2bf(oo * tanhs(c));
    }
    __threadfence();    // all waves: drain stores + L2 writeback (cross-XCD visibility)
    __syncthreads();
    if (tid == 0)
      __hip_atomic_fetch_add(fl_my + t, 1u, __ATOMIC_RELEASE, __HIP_MEMORY_SCOPE_AGENT);
  }
}

// out^T-tiled FC: D[c,b] += fc_w[c,k] * y2[b,k]; 32 c-tiles x 32 k-chunks, atomic f32 adds.
__launch_bounds__(256)
__global__ void fc_kernel(const float* __restrict__ w, const unsigned short* __restrict__ y2,
                          float* __restrict__ out) {
  const int ct = blockIdx.x & 31;
  const int kch = blockIdx.x >> 5;
  const int tid = threadIdx.x, lane = tid & 63, wvv = tid >> 6;
  const int b = wvv * 16 + (lane & 15);
  const int KT = Tt * Hh;  // 131072
  const int kbase = kch * 4096 + (lane >> 4) * 8;
  const int c0 = ct * 32 + (lane & 15);
  const int c1 = c0 + 16;
  const bool v0 = (c0 < Cc), v1 = (c1 < Cc);
  const float* w0 = w + (size_t)c0 * KT;
  const float* w1 = w + (size_t)c1 * KT;
  const unsigned short* yr = y2 + (size_t)b * KT;
  f4 a0 = {0.f, 0.f, 0.f, 0.f}, a1 = {0.f, 0.f, 0.f, 0.f};
  for (int kk = 0; kk < 4096; kk += 32) {
    const int k = kbase + kk;
    s8 bf = *(const s8*)(yr + k);
    s8 wa0 = {0, 0, 0, 0, 0, 0, 0, 0}, wa1 = {0, 0, 0, 0, 0, 0, 0, 0};
    if (v0) {
#pragma unroll
      for (int q = 0; q < 8; ++q) wa0[q] = (short)f2bf(w0[k + q]);
    }
    if (v1) {
#pragma unroll
      for (int q = 0; q < 8; ++q) wa1[q] = (short)f2bf(w1[k + q]);
    }
    a0 = __builtin_amdgcn_mfma_f32_16x16x32_bf16(wa0, bf, a0, 0, 0, 0);
    a1 = __builtin_amdgcn_mfma_f32_16x16x32_bf16(wa1, bf, a1, 0, 0, 0);
  }
  const int rr = (lane >> 4) * 4;
#pragma unroll
  for (int q = 0; q < 4; ++q) {
    int ca = ct * 32 + rr + q;
    if (ca < Cc) atomicAdd(out + (size_t)b * Cc + ca, a0[q]);
    int cb2 = ca + 16;
    if (cb2 < Cc) atomicAdd(out + (size_t)b * Cc + cb2, a1[q]);
  }
}

extern "C" void kernel_launch(void* const* d_in, const int* in_sizes, int n_in,
                              void* d_out, int out_size, void* d_ws, size_t ws_size,
                              hipStream_t stream) {
  const float* x = (const float*)d_in[0];
  LP p;
  p.Wih[0] = (const float*)d_in[1];  p.Whh[0] = (const float*)d_in[2];
  p.bih[0] = (const float*)d_in[3];  p.bhh[0] = (const float*)d_in[4];
  p.Wih[1] = (const float*)d_in[5];  p.Whh[1] = (const float*)d_in[6];
  p.bih[1] = (const float*)d_in[7];  p.bhh[1] = (const float*)d_in[8];
  p.Wih[2] = (const float*)d_in[9];  p.Whh[2] = (const float*)d_in[10];
  p.bih[2] = (const float*)d_in[11]; p.bhh[2] = (const float*)d_in[12];
  const float* fcw = (const float*)d_in[13];
  const float* fcb = (const float*)d_in[14];

  char* ws = (char*)d_ws;
  const size_t ysz = (size_t)Bb * Tt * Hh;  // elements per y buffer
  unsigned short* y0 = (unsigned short*)ws;
  unsigned short* y1 = y0 + ysz;
  unsigned short* y2 = y1 + ysz;
  unsigned* flags = (unsigned*)(ws + 3 * ysz * 2);
  unsigned short* xb = (unsigned short*)(ws + 3 * ysz * 2 + 4096);
  p.y0 = y0; p.y1 = y1; p.y2 = y2; p.flags = flags; p.xb = xb;

  zero_flags<<<1, 256, 0, stream>>>(flags);
  cvt_x_kernel<<<2048, 256, 0, stream>>>(x, xb);
  bias_init_kernel<<<250, 256, 0, stream>>>(fcb, (float*)d_out);
  lstm_kernel<<<192, 256, 0, stream>>>(p);
  fc_kernel<<<1024, 256, 0, stream>>>(fcw, y2, (float*)d_out);
}

// Round 2
// 2315.114 us; speedup vs baseline: 3.7427x; 3.7427x over previous
//
#include <hip/hip_runtime.h>
#include <hip/hip_bf16.h>

#define Bb 64
#define Tt 256
#define Ii 256
#define Hh 512
#define Cc 1000

typedef float f4 __attribute__((ext_vector_type(4)));
typedef short s8 __attribute__((ext_vector_type(8)));

__device__ __forceinline__ unsigned short f2bf(float f) {
  union { float f; unsigned u; } v; v.f = f;
  return (unsigned short)((v.u + 0x7FFFu + ((v.u >> 16) & 1u)) >> 16);
}
__device__ __forceinline__ float sigf(float x) {
  return __builtin_amdgcn_rcpf(1.f + __expf(-x));
}
__device__ __forceinline__ float tanhs(float x) {
  float ax = fabsf(x);
  float e = __expf(-2.f * ax);
  float r = (1.f - e) * __builtin_amdgcn_rcpf(1.f + e);
  return copysignf(r, x);
}

struct LP {
  const float* Wih[3]; const float* Whh[3];
  const float* bih[3]; const float* bhh[3];
  const unsigned short* xb;
  unsigned short* y0; unsigned short* y1; unsigned short* y2;
  unsigned* flags;  // [3][64] per-producer monotonic: flag = last completed t + 1
};

__global__ void zero_flags(unsigned* f) {
  for (int i = threadIdx.x; i < 256; i += 256) f[i] = 0;
}

__global__ void cvt_x_kernel(const float* __restrict__ x, unsigned short* __restrict__ xb) {
  int i = blockIdx.x * 256 + threadIdx.x;  // 524288 groups of 8 floats
  const float* s = x + (size_t)i * 8;
  s8 t;
#pragma unroll
  for (int q = 0; q < 8; ++q) t[q] = (short)f2bf(s[q]);
  *(s8*)(xb + (size_t)i * 8) = t;
}

__global__ void bias_init_kernel(const float* __restrict__ fcb, float* __restrict__ out) {
  int i = blockIdx.x * 256 + threadIdx.x;
  if (i < Bb * Cc) out[i] = fcb[i % Cc];
}

// 192 blocks: block = layer*64 + n-slice.  Each block: 8 h-columns x 64 batches,
// weights (32 gate-rows x K) bf16 in LDS, c-state in regs, flag-synced scan over t.
// Sync protocol: h stores are agent-scope (sc1, write-through to LLC); per-block
// monotonic flags; consumers poll flags wave-parallel and read h via normal cached
// loads (lines are write-once per dispatch and only read after flag release).
__launch_bounds__(256)
__global__ void lstm_kernel(LP p) {
  const int bid = blockIdx.x;
  const int layer = bid >> 6;
  const int n0 = (bid & 63) * 8;
  const int tid = threadIdx.x;
  const int lane = tid & 63;
  const int wv = tid >> 6;

  __shared__ unsigned short Wh[32 * Hh];  // 32 KB, XOR-swizzled
  __shared__ unsigned short Wi[32 * Hh];  // 32 KB (layer0 uses 32x256)

  const int Kin = (layer == 0) ? Ii : Hh;

  // LDS row r (r = tile*16 + rl): gate g = rl&3, n' = 2*(rl>>2) + tile
  // => tile0 rows compute even n, tile1 odd n (lane's two h values adjacent).
  {  // stage W_hh slice -> LDS (fp32 -> bf16, swizzle ((r&7)<<4) on byte addr)
    const float* wsrc = p.Whh[layer];
    for (int idx = tid; idx < 32 * (Hh / 8); idx += 256) {
      int r = idx >> 6;
      int kk = (idx & 63) << 3;
      int rl = r & 15, ts = r >> 4;
      int j = (rl & 3) * Hh + n0 + 2 * (rl >> 2) + ts;
      const float* s = wsrc + (size_t)j * Hh + kk;
      s8 t;
#pragma unroll
      for (int q = 0; q < 8; ++q) t[q] = (short)f2bf(s[q]);
      int byt = ((r * Hh + kk) * 2) ^ ((r & 7) << 4);
      *(s8*)((char*)Wh + byt) = t;
    }
    const float* wsi = p.Wih[layer];
    int kd8 = Kin >> 3;
    for (int idx = tid; idx < 32 * kd8; idx += 256) {
      int r = idx / kd8;
      int kk = (idx - r * kd8) << 3;
      int rl = r & 15, ts = r >> 4;
      int j = (rl & 3) * Hh + n0 + 2 * (rl >> 2) + ts;
      const float* s = wsi + (size_t)j * Kin + kk;
      s8 t;
#pragma unroll
      for (int q = 0; q < 8; ++q) t[q] = (short)f2bf(s[q]);
      int byt = ((r * Kin + kk) * 2) ^ ((r & 7) << 4);
      *(s8*)((char*)Wi + byt) = t;
    }
  }

  const int nn = lane >> 4;  // 0..3
  float bv0[4], bv1[4];
  {
#pragma unroll
    for (int g = 0; g < 4; ++g) {
      bv0[g] = p.bih[layer][g * Hh + n0 + 2 * nn] + p.bhh[layer][g * Hh + n0 + 2 * nn];
      bv1[g] = p.bih[layer][g * Hh + n0 + 2 * nn + 1] + p.bhh[layer][g * Hh + n0 + 2 * nn + 1];
    }
  }
  float cs0 = 0.f, cs1 = 0.f;
  __syncthreads();

  const int bmine = wv * 16 + (lane & 15);   // this lane's batch (B-frag col)
  const int ksub = (lane >> 4) * 8;          // k offset inside 32-chunk
  const int arow = lane & 15;                // A-frag row within tile
  const int aswz = (arow & 7) << 4;

  unsigned short* ybufs[3] = {p.y0, p.y1, p.y2};
  unsigned short* yl = ybufs[layer];
  const unsigned short* yin = (layer == 0) ? p.xb : ybufs[layer - 1];
  const size_t yin_row = (layer == 0) ? (size_t)(Tt * Ii) : (size_t)(Tt * Hh);
  unsigned* fl_own = p.flags + layer * 64;
  unsigned* fl_in = p.flags + (layer - 1) * 64;
  unsigned* myflag = fl_own + (bid & 63);

  for (int t = 0; t < Tt; ++t) {
    // wave-parallel flag polls: lane l watches producer block l
    if (t > 0 && wv == 0) {
      while (__hip_atomic_load(fl_own + lane, __ATOMIC_RELAXED, __HIP_MEMORY_SCOPE_AGENT) <
             (unsigned)t)
        __builtin_amdgcn_s_sleep(1);
    }
    if (layer > 0 && wv == 1) {
      while (__hip_atomic_load(fl_in + lane, __ATOMIC_RELAXED, __HIP_MEMORY_SCOPE_AGENT) <
             (unsigned)(t + 1))
        __builtin_amdgcn_s_sleep(1);
    }
    __syncthreads();

    f4 a0 = {0.f, 0.f, 0.f, 0.f};
    f4 a1 = {0.f, 0.f, 0.f, 0.f};

    if (t > 0) {  // recurrent: gates^T += Whh_slice * h[t-1]^T  (cached loads)
      const unsigned short* hr = yl + ((size_t)bmine * Tt + (t - 1)) * Hh + ksub;
#pragma unroll 4
      for (int kc = 0; kc < 16; ++kc) {
        s8 bf = *(const s8*)(hr + kc * 32);
        int cb = kc * 64 + ksub * 2;
        s8 wa0 = *(const s8*)((const char*)Wh + ((arow * 1024 + cb) ^ aswz));
        s8 wa1 = *(const s8*)((const char*)Wh + (((arow + 16) * 1024 + cb) ^ aswz));
        a0 = __builtin_amdgcn_mfma_f32_16x16x32_bf16(wa0, bf, a0, 0, 0, 0);
        a1 = __builtin_amdgcn_mfma_f32_16x16x32_bf16(wa1, bf, a1, 0, 0, 0);
      }
    }
    {  // input: gates^T += Wih_slice * in[t]^T
      const unsigned short* xr = yin + (size_t)bmine * yin_row + (size_t)t * Kin + ksub;
      if (layer == 0) {
#pragma unroll 4
        for (int kc = 0; kc < 8; ++kc) {
          s8 bf = *(const s8*)(xr + kc * 32);
          int cb = kc * 64 + ksub * 2;
          s8 wa0 = *(const s8*)((const char*)Wi + ((arow * 512 + cb) ^ aswz));
          s8 wa1 = *(const s8*)((const char*)Wi + (((arow + 16) * 512 + cb) ^ aswz));
          a0 = __builtin_amdgcn_mfma_f32_16x16x32_bf16(wa0, bf, a0, 0, 0, 0);
          a1 = __builtin_amdgcn_mfma_f32_16x16x32_bf16(wa1, bf, a1, 0, 0, 0);
        }
      } else {
#pragma unroll 4
        for (int kc = 0; kc < 16; ++kc) {
          s8 bf = *(const s8*)(xr + kc * 32);
          int cb = kc * 64 + ksub * 2;
          s8 wa0 = *(const s8*)((const char*)Wi + ((arow * 1024 + cb) ^ aswz));
          s8 wa1 = *(const s8*)((const char*)Wi + (((arow + 16) * 1024 + cb) ^ aswz));
          a0 = __builtin_amdgcn_mfma_f32_16x16x32_bf16(wa0, bf, a0, 0, 0, 0);
          a1 = __builtin_amdgcn_mfma_f32_16x16x32_bf16(wa1, bf, a1, 0, 0, 0);
        }
      }
    }

    // pointwise LSTM: a0 = {i,f,g,o} at n = n0+2*nn (even), a1 at n0+2*nn+1 (odd)
    {
      float pi = a0[0] + bv0[0], pf = a0[1] + bv0[1], pg = a0[2] + bv0[2], po = a0[3] + bv0[3];
      float ii = sigf(pi), ff = sigf(pf), gg = tanhs(pg), oo = sigf(po);
      float c = ff * cs0 + ii * gg; cs0 = c;
      float he = oo * tanhs(c);
      pi = a1[0] + bv1[0]; pf = a1[1] + bv1[1]; pg = a1[2] + bv1[2]; po = a1[3] + bv1[3];
      ii = sigf(pi); ff = sigf(pf); gg = tanhs(pg); oo = sigf(po);
      c = ff * cs1 + ii * gg; cs1 = c;
      float ho = oo * tanhs(c);
      unsigned hv = (unsigned)f2bf(he) | ((unsigned)f2bf(ho) << 16);
      unsigned* yw32 = (unsigned*)(yl + ((size_t)bmine * Tt + t) * Hh + n0 + 2 * nn);
      // agent-scope store: write-through to LLC, no cache-wide maintenance
      __hip_atomic_store(yw32, hv, __ATOMIC_RELAXED, __HIP_MEMORY_SCOPE_AGENT);
    }
    __syncthreads();  // implicit vmcnt(0) drain: all h stores acked at LLC
    if (tid == 0)
      __hip_atomic_store(myflag, (unsigned)(t + 1), __ATOMIC_RELAXED, __HIP_MEMORY_SCOPE_AGENT);
  }
}

// out^T-tiled FC: D[c,b] += fc_w[c,k] * y2[b,k]; 32 c-tiles x 32 k-chunks, atomic f32 adds.
__launch_bounds__(256)
__global__ void fc_kernel(const float* __restrict__ w, const unsigned short* __restrict__ y2,
                          float* __restrict__ out) {
  const int ct = blockIdx.x & 31;
  const int kch = blockIdx.x >> 5;
  const int tid = threadIdx.x, lane = tid & 63, wvv = tid >> 6;
  const int b = wvv * 16 + (lane & 15);
  const int KT = Tt * Hh;  // 131072
  const int kbase = kch * 4096 + (lane >> 4) * 8;
  const int c0 = ct * 32 + (lane & 15);
  const int c1 = c0 + 16;
  const bool v0 = (c0 < Cc), v1 = (c1 < Cc);
  const float* w0 = w + (size_t)c0 * KT;
  const float* w1 = w + (size_t)c1 * KT;
  const unsigned short* yr = y2 + (size_t)b * KT;
  f4 a0 = {0.f, 0.f, 0.f, 0.f}, a1 = {0.f, 0.f, 0.f, 0.f};
  for (int kk = 0; kk < 4096; kk += 32) {
    const int k = kbase + kk;
    s8 bf = *(const s8*)(yr + k);
    s8 wa0 = {0, 0, 0, 0, 0, 0, 0, 0}, wa1 = {0, 0, 0, 0, 0, 0, 0, 0};
    if (v0) {
#pragma unroll
      for (int q = 0; q < 8; ++q) wa0[q] = (short)f2bf(w0[k + q]);
    }
    if (v1) {
#pragma unroll
      for (int q = 0; q < 8; ++q) wa1[q] = (short)f2bf(w1[k + q]);
    }
    a0 = __builtin_amdgcn_mfma_f32_16x16x32_bf16(wa0, bf, a0, 0, 0, 0);
    a1 = __builtin_amdgcn_mfma_f32_16x16x32_bf16(wa1, bf, a1, 0, 0, 0);
  }
  const int rr = (lane >> 4) * 4;
#pragma unroll
  for (int q = 0; q < 4; ++q) {
    int ca = ct * 32 + rr + q;
    if (ca < Cc) atomicAdd(out + (size_t)b * Cc + ca, a0[q]);
    int cb2 = ca + 16;
    if (cb2 < Cc) atomicAdd(out + (size_t)b * Cc + cb2, a1[q]);
  }
}

extern "C" void kernel_launch(void* const* d_in, const int* in_sizes, int n_in,
                              void* d_out, int out_size, void* d_ws, size_t ws_size,
                              hipStream_t stream) {
  const float* x = (const float*)d_in[0];
  LP p;
  p.Wih[0] = (const float*)d_in[1];  p.Whh[0] = (const float*)d_in[2];
  p.bih[0] = (const float*)d_in[3];  p.bhh[0] = (const float*)d_in[4];
  p.Wih[1] = (const float*)d_in[5];  p.Whh[1] = (const float*)d_in[6];
  p.bih[1] = (const float*)d_in[7];  p.bhh[1] = (const float*)d_in[8];
  p.Wih[2] = (const float*)d_in[9];  p.Whh[2] = (const float*)d_in[10];
  p.bih[2] = (const float*)d_in[11]; p.bhh[2] = (const float*)d_in[12];
  const float* fcw = (const float*)d_in[13];
  const float* fcb = (const float*)d_in[14];

  char* ws = (char*)d_ws;
  const size_t ysz = (size_t)Bb * Tt * Hh;  // elements per y buffer
  unsigned short* y0 = (unsigned short*)ws;
  unsigned short* y1 = y0 + ysz;
  unsigned short* y2 = y1 + ysz;
  unsigned* flags = (unsigned*)(ws + 3 * ysz * 2);
  unsigned short* xb = (unsigned short*)(ws + 3 * ysz * 2 + 4096);
  p.y0 = y0; p.y1 = y1; p.y2 = y2; p.flags = flags; p.xb = xb;

  zero_flags<<<1, 256, 0, stream>>>(flags);
  cvt_x_kernel<<<2048, 256, 0, stream>>>(x, xb);
  bias_init_kernel<<<250, 256, 0, stream>>>(fcb, (float*)d_out);
  lstm_kernel<<<192, 256, 0, stream>>>(p);
  fc_kernel<<<1024, 256, 0, stream>>>(fcw, y2, (float*)d_out);
}